// Round 20
// baseline (2029.408 us; speedup 1.0000x reference)
//
#include <hip/hip_runtime.h>

typedef unsigned short u16;
typedef unsigned int u32;
typedef unsigned long long u64;
typedef __attribute__((ext_vector_type(4))) float f32x4;
typedef __attribute__((ext_vector_type(8))) short s16x8;
typedef __attribute__((ext_vector_type(4))) int i32x4;

#define EPS 1e-5f

// ---------- helpers ----------
__device__ __forceinline__ u16 f2bf(float f) {
  unsigned u = __float_as_uint(f);
  return (u16)((u + 0x7fffu + ((u >> 16) & 1u)) >> 16);
}
__device__ __forceinline__ float sigm(float x) { return 1.0f / (1.0f + __expf(-x)); }
__device__ __forceinline__ float tanh_f(float x) {
  float e = __expf(-2.0f * fabsf(x));
  float r = (1.0f - e) / (1.0f + e);
  return copysignf(r, x);
}
__device__ __forceinline__ void gl_lds16(const void* g, void* l) {
  __builtin_amdgcn_global_load_lds(
      (const __attribute__((address_space(1))) u32*)g,
      (__attribute__((address_space(3))) u32*)l, 16, 0, 0);
}

// ---------- merged setup: weight pack + x transpose + zero flags ----------
// bid<1920: wcvt; 1920..2943: xtrans; 2944..2951: zero flags
__global__ __launch_bounds__(256) void k_setup(
    const float* __restrict__ cw, u16* __restrict__ Wpk,
    const float* __restrict__ x, u16* __restrict__ xT, i32x4* __restrict__ flz) {
  const int bid = blockIdx.x, tid = threadIdx.x;
  __shared__ __align__(16) u16 ltile[256 * 72];
  if (bid < 1920) {
    // f = (tap*6+kk)*32 + of ; of = gate-ch>>4 = g*8 + ch16 ; element = lane*8+j
    // A[o][c]: o = of*16 + (lane&15), c = kk*32 + (lane>>4)*8 + j
    int idx = bid * 256 + tid;                 // exactly 491520
    int f = idx >> 9, r = idx & 511;
    int lane = r >> 3, j = r & 7;
    int of = f & 31, tk = f >> 5;
    int kk = tk % 6, tap = tk / 6;
    int o = (of << 4) + (lane & 15);
    int c = (kk << 5) + ((lane >> 4) << 3) + j;
    Wpk[idx] = f2bf(cw[(o * 192 + c) * 5 + tap]);
  } else if (bid < 2944) {
    // x (t,b,64,256) f32 -> xT[t*32+b][264 rows][64 ch] bf16, swizzled, halos zeroed
    int tb = bid - 1920;
    const float* src = x + tb * (64 * 256);
    for (int it = 0; it < 64; ++it) {
      int idx = it * 256 + tid;
      int c = idx >> 8, l = idx & 255;
      ltile[l * 72 + c] = f2bf(src[idx]);
    }
    __syncthreads();
    char* dst = (char*)(xT + tb * 16896);
    i32x4 z = {0, 0, 0, 0};
    for (int i = tid; i < 2112; i += 256) {    // 264 rows x 8 chunks
      int r = i >> 3, ch = i & 7;
      i32x4 v = z;
      if (r >= 2 && r < 258) v = *(const i32x4*)(ltile + (r - 2) * 72 + ch * 8);
      *(i32x4*)(dst + r * 128 + ((ch * 16) ^ ((r & 7) << 4))) = v;
    }
  } else {
    int base = (bid - 2944) * 256 + tid;       // 2048 threads
    i32x4 z = {0, 0, 0, 0};
    if (base < 1024) flz[base] = z;            // 4096 epoch flags (16 ints/block pad)
  }
}

// ---------- single mega dispatch: ALL 32 steps; halo-decomposed, fence-free ----------
// grid 256: bid = (lq<<5) | b. Block: ALL 512 gate-ch x 32 L (slice lq); 8 waves, wave = ch16.
// h lives in ldsh (36 rows: 2 lo-halo + 32 own + 2 hi-halo); cx in registers.
// Cross-block per step: stats 8-way + halo 2-way, both via relaxed agent atomics
// (coherence-point, NO fences) + monotonic epoch flags. All deterministic.
__global__ __launch_bounds__(512, 2) void k_all(
    const u16* __restrict__ Wpk, const u16* __restrict__ xT,
    const float* __restrict__ cb, const float* __restrict__ gnw, const float* __restrict__ gnb,
    float* __restrict__ out, float* __restrict__ statsB, u32* __restrict__ haloB,
    int* __restrict__ flags) {
  const int bid = blockIdx.x;
  const int b = bid & 31, lq = bid >> 5;
  const int L0 = lq << 5;
  const int tid = threadIdx.x, wave = tid >> 6, lane = tid & 63;   // wave = ch16 strip
  const int l15 = lane & 15, q = lane >> 4;
  const int cgrp = q << 4;

  __shared__ __align__(16) char ldsx[4608];    // 36 rows x 128 B (x, swizzled)
  __shared__ __align__(16) char ldsh[9216];    // 36 rows x 256 B (h, swizzled; halos at 0,1,34,35)
  __shared__ float red[8][4][2];
  __shared__ float sred[32];
  __shared__ float smu[16], srs[16];

  // ---- step-invariant per-thread params; cx in registers ----
  const int chq = (wave << 4) + (q << 2);      // hy-ch base for r=0
  const int csg = wave >> 1;                   // GN cs for this wave's channels
  f32x4 biasv[4], w4[4], b4[4];
  #pragma unroll
  for (int g = 0; g < 4; ++g) {
    biasv[g] = *(const f32x4*)(cb  + (g << 7) + chq);
    w4[g]    = *(const f32x4*)(gnw + (g << 7) + chq);
    b4[g]    = *(const f32x4*)(gnb + (g << 7) + chq);
  }
  float cxr[2][4];
  #pragma unroll
  for (int ni = 0; ni < 2; ++ni)
    #pragma unroll
    for (int r = 0; r < 4; ++r) cxr[ni][r] = 0.f;

  // ---- entry: zero ldsh (h(0)=0 incl halos), stage x(0) ----
  {
    i32x4 z = {0, 0, 0, 0};
    for (int i = tid; i < 576; i += 512) ((i32x4*)ldsh)[i] = z;
    if (tid < 288)
      gl_lds16((const char*)(xT + b * 16896) + (L0 << 7) + (tid << 4), ldsx + (tid << 4));
  }
  asm volatile("s_waitcnt vmcnt(0)" ::: "memory");
  __syncthreads();

  const s16x8* Wv = (const s16x8*)Wpk;

  #pragma unroll 1
  for (int t = 0; t < 32; ++t) {
    // ---- conv K-loop: 30 chunks; A from L2 (wave-private panel), B from tiny LDS tiles ----
    f32x4 zero4 = {0.f, 0.f, 0.f, 0.f};
    f32x4 acc[4][2];
    #pragma unroll
    for (int g = 0; g < 4; ++g) { acc[g][0] = zero4; acc[g][1] = zero4; }

    #pragma unroll
    for (int tap = 0; tap < 5; ++tap) {
      #pragma unroll
      for (int kk = 0; kk < 6; ++kk) {
        const int cc = tap * 6 + kk;
        s16x8 av[4], bv[2];
        #pragma unroll
        for (int g = 0; g < 4; ++g)
          av[g] = Wv[(((cc << 5) + (g << 3) + wave) << 6) + lane];
        #pragma unroll
        for (int ni = 0; ni < 2; ++ni) {
          const int rr = (ni << 4) + l15 + tap;       // 0..35
          const int sw = (rr & 7) << 4;
          bv[ni] = (kk < 2)
            ? *(const s16x8*)(ldsx + (rr << 7) + (((kk << 6) + cgrp) ^ sw))
            : *(const s16x8*)(ldsh + (rr << 8) + ((((kk - 2) << 6) + cgrp) ^ sw));
        }
        #pragma unroll
        for (int g = 0; g < 4; ++g) {
          acc[g][0] = __builtin_amdgcn_mfma_f32_16x16x32_bf16(av[g], bv[0], acc[g][0], 0, 0, 0);
          acc[g][1] = __builtin_amdgcn_mfma_f32_16x16x32_bf16(av[g], bv[1], acc[g][1], 0, 0, 0);
        }
      }
    }

    // ---- +bias, per-wave partial stats (16 ch x 32 L) ----
    float sum4[4], sq4[4];
    #pragma unroll
    for (int g = 0; g < 4; ++g) {
      sum4[g] = 0.f; sq4[g] = 0.f;
      #pragma unroll
      for (int ni = 0; ni < 2; ++ni)
        #pragma unroll
        for (int r = 0; r < 4; ++r) {
          float v = acc[g][ni][r] + biasv[g][r];
          acc[g][ni][r] = v;
          sum4[g] += v; sq4[g] += v * v;
        }
    }
    #pragma unroll
    for (int off = 1; off < 64; off <<= 1) {
      #pragma unroll
      for (int g = 0; g < 4; ++g) {
        sum4[g] += __shfl_xor(sum4[g], off);
        sq4[g]  += __shfl_xor(sq4[g], off);
      }
    }
    if (lane == 0) {
      #pragma unroll
      for (int g = 0; g < 4; ++g) { red[wave][g][0] = sum4[g]; red[wave][g][1] = sq4[g]; }
    }
    __syncthreads();

    // ---- sync 1: 8-way stats exchange (relaxed atomics, slot parity t&1, no fences) ----
    const int par = t & 1;
    if (tid < 32) {   // value j: g = j>>3, cs = (j>>1)&3, comp = j&1 (block partial: 32ch x 32L)
      const int g = tid >> 3, cs = (tid >> 1) & 3, comp = tid & 1;
      float v = red[(cs << 1)][g][comp] + red[(cs << 1) | 1][g][comp];
      __hip_atomic_store(statsB + (((bid << 1) | par) << 5) + tid, v,
                         __ATOMIC_RELAXED, __HIP_MEMORY_SCOPE_AGENT);
    }
    __syncthreads();   // drain stores (syncthreads waits vmcnt)
    if (tid == 0)
      __hip_atomic_store(flags + (bid << 4), 2 * t + 1, __ATOMIC_RELEASE, __HIP_MEMORY_SCOPE_AGENT);
    // x(t+1) prefetch overlaps the spin (ldsx free since conv done)
    if (t < 31 && tid < 288)
      gl_lds16((const char*)(xT + (((t + 1) << 5) + b) * 16896) + (L0 << 7) + (tid << 4),
               ldsx + (tid << 4));
    if (tid < 7) {
      const int p = tid + (tid >= lq ? 1 : 0);
      const int* pf = flags + (((p << 5) | b) << 4);
      while (__hip_atomic_load(pf, __ATOMIC_RELAXED, __HIP_MEMORY_SCOPE_AGENT) < 2 * t + 1)
        __builtin_amdgcn_s_sleep(2);
    }
    __syncthreads();
    if (tid < 32) {    // fixed-order 8-slot gather -> deterministic
      float s = 0.f;
      #pragma unroll
      for (int p = 0; p < 8; ++p)
        s += __hip_atomic_load(statsB + ((((p << 5) | b) << 1 | par) << 5) + tid,
                               __ATOMIC_RELAXED, __HIP_MEMORY_SCOPE_AGENT);
      sred[tid] = s;
    }
    __syncthreads();
    if (tid < 16) {
      const float inv = 1.0f / 8192.0f;
      float s = sred[tid << 1], qv = sred[(tid << 1) | 1];
      float m = s * inv;
      smu[tid] = m;
      srs[tid] = rsqrtf(qv * inv - m * m + EPS);
    }
    __syncthreads();

    // ---- GN apply + LSTM pointwise (thread-local); h -> own ldsh rows ----
    const float mu0 = smu[csg],      rs0 = srs[csg];
    const float mu1 = smu[4 + csg],  rs1 = srs[4 + csg];
    const float mu2 = smu[8 + csg],  rs2 = srs[8 + csg];
    const float mu3 = smu[12 + csg], rs3 = srs[12 + csg];
    float* outp = out + (((t << 5) + b) << 15);
    #pragma unroll
    for (int ni = 0; ni < 2; ++ni) {
      const int l = L0 + (ni << 4) + l15;
      const int row = (ni << 4) + l15 + 2;
      u16 hp[4];
      #pragma unroll
      for (int r = 0; r < 4; ++r) {
        const int c = chq + r;
        float vi = (acc[0][ni][r] - mu0) * rs0 * w4[0][r] + b4[0][r];
        float vf = (acc[1][ni][r] - mu1) * rs1 * w4[1][r] + b4[1][r];
        float vg = (acc[2][ni][r] - mu2) * rs2 * w4[2][r] + b4[2][r];
        float vo = (acc[3][ni][r] - mu3) * rs3 * w4[3][r] + b4[3][r];
        float cyv = sigm(vf) * cxr[ni][r] + sigm(vi) * tanh_f(vg);
        float hyv = sigm(vo) * tanh_f(cyv);
        cxr[ni][r] = cyv;
        const int ci = (c << 8) + l;
        outp[ci] = hyv;
        hp[r] = f2bf(hyv);
        if (t == 31) {
          out[33554432 + (b << 15) + ci] = hyv;   // final hy
          out[34603008 + (b << 15) + ci] = cyv;   // final cy
        }
      }
      // 8B h store into ldsh at ch-byte off = wave*32+q*8, granule-XOR swizzled by row
      const int off = (wave << 5) + (q << 3);
      *(u64*)(ldsh + (row << 8) + ((((off >> 4) << 4) ^ ((row & 7) << 4)) | (off & 15))) =
          *(const u64*)hp;
    }

    if (t < 31) {
      __syncthreads();   // h(t+1) rows 2..33 visible
      // ---- sync 2: 2-way halo exchange (4 boundary rows, 1KB, relaxed atomics) ----
      if (tid < 256) {   // send: side 0 = rows 2,3 (for left nb), side 1 = rows 32,33 (for right)
        const int side = tid >> 7, k = tid & 127;
        const int rsel = k >> 6, cp = k & 63;
        const int row = (side ? 32 : 2) + rsel;
        u32 v = *(const u32*)(ldsh + (row << 8) +
                 ((((cp >> 2) << 4) ^ ((row & 7) << 4)) | ((cp << 2) & 15)));
        __hip_atomic_store(haloB + (((((bid << 1) | par) << 1) | side) << 7) + k, v,
                           __ATOMIC_RELAXED, __HIP_MEMORY_SCOPE_AGENT);
      }
      __syncthreads();   // drain
      if (tid == 0)
        __hip_atomic_store(flags + (bid << 4), 2 * t + 2, __ATOMIC_RELEASE, __HIP_MEMORY_SCOPE_AGENT);
      if (tid < 2) {
        const int nlq = lq + (tid ? 1 : -1);
        if (nlq >= 0 && nlq < 8) {
          const int* pf = flags + (((nlq << 5) | b) << 4);
          while (__hip_atomic_load(pf, __ATOMIC_RELAXED, __HIP_MEMORY_SCOPE_AGENT) < 2 * t + 2)
            __builtin_amdgcn_s_sleep(2);
        }
      }
      __syncthreads();
      if ((tid & 255) < 128) {   // recv: tid<128 left->rows 0,1 ; tid 256..383 right->rows 34,35
        const int rightn = tid >> 8, k = tid & 127;
        const int rsel = k >> 6, cp = k & 63;
        const int nlq = lq + (rightn ? 1 : -1);
        if (nlq >= 0 && nlq < 8) {
          const int nbid = (nlq << 5) | b;
          const int side = rightn ? 0 : 1;   // take right nb's bottom / left nb's top
          u32 v = __hip_atomic_load(haloB + (((((nbid << 1) | par) << 1) | side) << 7) + k,
                                    __ATOMIC_RELAXED, __HIP_MEMORY_SCOPE_AGENT);
          const int row = (rightn ? 34 : 0) + rsel;
          *(u32*)(ldsh + (row << 8) +
                  ((((cp >> 2) << 4) ^ ((row & 7) << 4)) | ((cp << 2) & 15))) = v;
        }
      }
      __syncthreads();   // halo ds_writes + x prefetch drained
    }
  }
}

// ---------- launch ----------
extern "C" void kernel_launch(void* const* d_in, const int* in_sizes, int n_in,
                              void* d_out, int out_size, void* d_ws, size_t ws_size,
                              hipStream_t stream) {
  const float* x  = (const float*)d_in[0];
  const float* cw = (const float*)d_in[1];
  const float* cb = (const float*)d_in[2];
  const float* gw = (const float*)d_in[3];
  const float* gb = (const float*)d_in[4];
  float* out = (float*)d_out;
  char* ws = (char*)d_ws;

  u16*   Wpk    = (u16*)(ws);                 //     983,040 B
  u16*   xT     = (u16*)(ws + 983040);        //  34,603,008 B
  float* statsB = (float*)(ws + 35586048);    //      65,536 B (256 blk x 2 par x 32 f32)
  u32*   haloB  = (u32*)(ws + 35651584);      //     524,288 B (256 x 2 x 2 x 128 u32)
  int*   flags  = (int*)(ws + 36175872);      //      16,384 B (monotonic epochs) (~36.2 MB)

  k_setup<<<2952, 256, 0, stream>>>(cw, Wpk, x, xT, (i32x4*)flags);
  k_all<<<256, 512, 0, stream>>>(Wpk, xT, cb, gw, gb, out, statsB, haloB, flags);
}

// Round 21
// 664.782 us; speedup vs baseline: 3.0527x; 3.0527x over previous
//
#include <hip/hip_runtime.h>

typedef unsigned short u16;
typedef unsigned int u32;
typedef unsigned long long u64;
typedef __attribute__((ext_vector_type(4))) float f32x4;
typedef __attribute__((ext_vector_type(8))) short s16x8;
typedef __attribute__((ext_vector_type(4))) int i32x4;

#define EPS 1e-5f

// ---------- helpers ----------
__device__ __forceinline__ u16 f2bf(float f) {
  unsigned u = __float_as_uint(f);
  return (u16)((u + 0x7fffu + ((u >> 16) & 1u)) >> 16);
}
__device__ __forceinline__ float sigm(float x) { return 1.0f / (1.0f + __expf(-x)); }
__device__ __forceinline__ float tanh_f(float x) {
  float e = __expf(-2.0f * fabsf(x));
  float r = (1.0f - e) / (1.0f + e);
  return copysignf(r, x);
}
__device__ __forceinline__ void gl_lds16(const void* g, void* l) {
  __builtin_amdgcn_global_load_lds(
      (const __attribute__((address_space(1))) u32*)g,
      (__attribute__((address_space(3))) u32*)l, 16, 0, 0);
}

// ---------- merged setup: weight pack + x transpose + zero ----------
// bid<1920: wcvt; 1920..2943: xtrans; 2944..3455: zero hT/cx/flags
__global__ __launch_bounds__(256) void k_setup(
    const float* __restrict__ cw, u16* __restrict__ Wpk,
    const float* __restrict__ x, u16* __restrict__ xT,
    i32x4* __restrict__ hTz, i32x4* __restrict__ cxz, i32x4* __restrict__ flz) {
  const int bid = blockIdx.x, tid = threadIdx.x;
  __shared__ __align__(16) u16 ltile[256 * 72];
  if (bid < 1920) {
    // f = (tap*6+kk)*32 + of ; of = gate-ch>>4 ; element = lane*8+j
    // A[o][c]: o = of*16 + (lane&15), c = kk*32 + (lane>>4)*8 + j
    int idx = bid * 256 + tid;                 // exactly 491520
    int f = idx >> 9, r = idx & 511;
    int lane = r >> 3, j = r & 7;
    int of = f & 31, tk = f >> 5;
    int kk = tk % 6, tap = tk / 6;
    int o = (of << 4) + (lane & 15);
    int c = (kk << 5) + ((lane >> 4) << 3) + j;
    Wpk[idx] = f2bf(cw[(o * 192 + c) * 5 + tap]);
  } else if (bid < 2944) {
    // x (t,b,64,256) f32 -> xT[t*32+b][264 rows][64 ch] bf16, swizzled, halos zeroed
    int tb = bid - 1920;
    const float* src = x + tb * (64 * 256);
    for (int it = 0; it < 64; ++it) {
      int idx = it * 256 + tid;
      int c = idx >> 8, l = idx & 255;
      ltile[l * 72 + c] = f2bf(src[idx]);
    }
    __syncthreads();
    char* dst = (char*)(xT + tb * 16896);
    i32x4 z = {0, 0, 0, 0};
    for (int i = tid; i < 2112; i += 256) {    // 264 rows x 8 chunks
      int r = i >> 3, ch = i & 7;
      i32x4 v = z;
      if (r >= 2 && r < 258) v = *(const i32x4*)(ltile + (r - 2) * 72 + ch * 8);
      *(i32x4*)(dst + r * 128 + ((ch * 16) ^ ((r & 7) << 4))) = v;
    }
  } else {
    int base = (bid - 2944) * 256 + tid;       // 131072 threads
    i32x4 z = {0, 0, 0, 0};
    for (int i = base; i < 270336; i += 131072) hTz[i] = z;   // hT both buffers
    for (int i = base; i < 262144; i += 131072) cxz[i] = z;   // cx
    for (int i = base; i < 2048;   i += 131072) flz[i] = z;   // 8192 flags
  }
}

// ---------- fused step: split-pipeline staging -> conv -> stats -> partner spin -> GN+LSTM ----------
// grid 256: bid = ((cs*2+lh)<<5) | b  (partner bid^32 on same XCD: bid%8 = b%8)
// block 512 = 8 waves (wm 2 x wl 4). Block: ch strip cs (32 hy-ch x 4 gates = M128) x 128 L (lh).
// K-loop split: x-chunks (kk<2) run while h staging is in flight (counted vmcnt, raw s_barrier).
__global__ __launch_bounds__(512) void k_step(
    const u16* __restrict__ Wpk, const u16* __restrict__ xT, u16* __restrict__ hT,
    const float* __restrict__ cb, const float* __restrict__ gnw, const float* __restrict__ gnb,
    float* __restrict__ cx, float* __restrict__ out,
    float* __restrict__ stats, int* __restrict__ flags, int t) {
  const int bid = blockIdx.x;
  const int b = bid & 31, lh = (bid >> 5) & 1, cs = bid >> 6;
  const int L0 = lh << 7;
  const int tid = threadIdx.x, wave = tid >> 6, lane = tid & 63;
  const int wm = wave & 1, wl = wave >> 1;
  const int l15 = lane & 15, q = lane >> 4;
  const int cgrp = q << 4;

  __shared__ __align__(16) char ldsx[16896];   // 132 rows x 128 B (x, swizzled)
  __shared__ __align__(16) char ldsh[33792];   // 132 rows x 256 B (h, swizzled)
  __shared__ __align__(16) char hl[8192];      // 128 l x 64 B (32 ch bf16, 8B-slot swizzled)
  __shared__ float red[8][4][2];
  __shared__ float blkstat[8];
  __shared__ float smu[4], srs[4];

  const u16* hTr = hT + (t & 1) * 1081344;
  u16* hTw = hT + ((t + 1) & 1) * 1081344;

  // ---- issue x(t) staging, then h(t) staging (async, ordered) ----
  {
    const char* gx = (const char*)(xT + ((t << 5) + b) * 16896) + (lh << 14);
    for (int i = tid; i < 1056; i += 512) gl_lds16(gx + (i << 4), ldsx + (i << 4));
  }
  __builtin_amdgcn_sched_barrier(0);
  {
    const char* gh = (const char*)hTr + b * 67584 + (lh << 15);
    for (int i = tid; i < 2112; i += 512) gl_lds16(gh + (i << 4), ldsh + (i << 4));
  }
  __builtin_amdgcn_sched_barrier(0);
  // wait for x only: every thread issued 4 or 5 h-loads -> vmcnt(4) drains all its x-loads
  asm volatile("s_waitcnt vmcnt(4)" ::: "memory");
  __builtin_amdgcn_s_barrier();
  __builtin_amdgcn_sched_barrier(0);

  f32x4 zero4 = {0.f, 0.f, 0.f, 0.f};
  f32x4 acc[4][2];
  #pragma unroll
  for (int g = 0; g < 4; ++g) { acc[g][0] = zero4; acc[g][1] = zero4; }

  const s16x8* Wv = (const s16x8*)Wpk;

  // ---- phase 1: 10 x-chunks (kk<2, ldsx only) while h staging lands ----
  #pragma unroll
  for (int tap = 0; tap < 5; ++tap) {
    #pragma unroll
    for (int kk = 0; kk < 2; ++kk) {
      const int cc = tap * 6 + kk;
      s16x8 av[4], bv[2];
      #pragma unroll
      for (int g = 0; g < 4; ++g) {
        const int of = (g << 3) + (cs << 1) + wm;
        av[g] = Wv[(((cc << 5) + of) << 6) + lane];
      }
      #pragma unroll
      for (int ni = 0; ni < 2; ++ni) {
        const int rr = (wl << 5) + (ni << 4) + l15 + tap;
        const int sw = (rr & 7) << 4;
        bv[ni] = *(const s16x8*)(ldsx + (rr << 7) + (((kk << 6) + cgrp) ^ sw));
      }
      #pragma unroll
      for (int g = 0; g < 4; ++g) {
        acc[g][0] = __builtin_amdgcn_mfma_f32_16x16x32_bf16(av[g], bv[0], acc[g][0], 0, 0, 0);
        acc[g][1] = __builtin_amdgcn_mfma_f32_16x16x32_bf16(av[g], bv[1], acc[g][1], 0, 0, 0);
      }
    }
  }
  __builtin_amdgcn_sched_barrier(0);
  asm volatile("s_waitcnt vmcnt(0)" ::: "memory");
  __builtin_amdgcn_s_barrier();
  __builtin_amdgcn_sched_barrier(0);

  // ---- phase 2: 20 h-chunks (kk2 0..3, ldsh) ----
  #pragma unroll
  for (int tap = 0; tap < 5; ++tap) {
    #pragma unroll
    for (int kk2 = 0; kk2 < 4; ++kk2) {
      const int cc = tap * 6 + kk2 + 2;
      s16x8 av[4], bv[2];
      #pragma unroll
      for (int g = 0; g < 4; ++g) {
        const int of = (g << 3) + (cs << 1) + wm;
        av[g] = Wv[(((cc << 5) + of) << 6) + lane];
      }
      #pragma unroll
      for (int ni = 0; ni < 2; ++ni) {
        const int rr = (wl << 5) + (ni << 4) + l15 + tap;
        const int sw = (rr & 7) << 4;
        bv[ni] = *(const s16x8*)(ldsh + (rr << 8) + (((kk2 << 6) + cgrp) ^ sw));
      }
      #pragma unroll
      for (int g = 0; g < 4; ++g) {
        acc[g][0] = __builtin_amdgcn_mfma_f32_16x16x32_bf16(av[g], bv[0], acc[g][0], 0, 0, 0);
        acc[g][1] = __builtin_amdgcn_mfma_f32_16x16x32_bf16(av[g], bv[1], acc[g][1], 0, 0, 0);
      }
    }
  }

  // ---- +bias, per-gate partial stats (strip cs x this 128L) ----
  const int chq = (cs << 5) + (wm << 4) + (q << 2);   // hy-ch base for r=0
  float sum4[4], sq4[4];
  #pragma unroll
  for (int g = 0; g < 4; ++g) {
    const f32x4 bias = *(const f32x4*)(cb + (g << 7) + chq);
    sum4[g] = 0.f; sq4[g] = 0.f;
    #pragma unroll
    for (int ni = 0; ni < 2; ++ni)
      #pragma unroll
      for (int r = 0; r < 4; ++r) {
        float v = acc[g][ni][r] + bias[r];
        acc[g][ni][r] = v;
        sum4[g] += v; sq4[g] += v * v;
      }
  }
  // preload pointwise params + cx (hides L2 latency under reduce+spin)
  f32x4 w4[4], b4[4];
  float cxv[2][4];
  #pragma unroll
  for (int g = 0; g < 4; ++g) {
    w4[g] = *(const f32x4*)(gnw + (g << 7) + chq);
    b4[g] = *(const f32x4*)(gnb + (g << 7) + chq);
  }
  #pragma unroll
  for (int ni = 0; ni < 2; ++ni) {
    const int l = L0 + (wl << 5) + (ni << 4) + l15;
    #pragma unroll
    for (int r = 0; r < 4; ++r)
      cxv[ni][r] = cx[(b << 15) + ((chq + r) << 8) + l];
  }
  #pragma unroll
  for (int off = 1; off < 64; off <<= 1) {
    #pragma unroll
    for (int g = 0; g < 4; ++g) {
      sum4[g] += __shfl_xor(sum4[g], off);
      sq4[g]  += __shfl_xor(sq4[g], off);
    }
  }
  if (lane == 0) {
    #pragma unroll
    for (int g = 0; g < 4; ++g) { red[wave][g][0] = sum4[g]; red[wave][g][1] = sq4[g]; }
  }
  __syncthreads();
  if (tid < 8) {
    const int g = tid >> 1, j = tid & 1;
    float v = 0.f;
    #pragma unroll
    for (int w = 0; w < 8; ++w) v += red[w][g][j];
    blkstat[tid] = v;
  }
  __syncthreads();

  // ---- partner spin (lh^1): 32B stats exchange; fresh slot per t; fixed-order sum ----
  const int sidx = (((t << 5) + b) << 3) + (cs << 1) + lh;
  if (tid == 0) {
    float* sp = stats + (sidx << 3);
    #pragma unroll
    for (int j = 0; j < 8; ++j)
      __hip_atomic_store(sp + j, blkstat[j], __ATOMIC_RELAXED, __HIP_MEMORY_SCOPE_AGENT);
    __hip_atomic_store(&flags[sidx], 1, __ATOMIC_RELEASE, __HIP_MEMORY_SCOPE_AGENT);
    while (__hip_atomic_load(&flags[sidx ^ 1], __ATOMIC_RELAXED, __HIP_MEMORY_SCOPE_AGENT) == 0)
      __builtin_amdgcn_s_sleep(2);
    __builtin_amdgcn_fence(__ATOMIC_ACQUIRE, "agent");
    const float* pe = stats + ((sidx & ~1) << 3);   // even lh first -> identical in both partners
    const float* po = stats + ((sidx | 1) << 3);
    const float inv = 1.0f / 8192.0f;
    #pragma unroll
    for (int g = 0; g < 4; ++g) {
      float s = __hip_atomic_load(pe + (g << 1), __ATOMIC_RELAXED, __HIP_MEMORY_SCOPE_AGENT)
              + __hip_atomic_load(po + (g << 1), __ATOMIC_RELAXED, __HIP_MEMORY_SCOPE_AGENT);
      float qv = __hip_atomic_load(pe + (g << 1) + 1, __ATOMIC_RELAXED, __HIP_MEMORY_SCOPE_AGENT)
               + __hip_atomic_load(po + (g << 1) + 1, __ATOMIC_RELAXED, __HIP_MEMORY_SCOPE_AGENT);
      float m = s * inv;
      smu[g] = m;
      srs[g] = rsqrtf(qv * inv - m * m + EPS);
    }
  }
  __syncthreads();

  // ---- GN apply + LSTM pointwise (thread-local, all 4 gates in registers) ----
  const float mu0 = smu[0], mu1 = smu[1], mu2 = smu[2], mu3 = smu[3];
  const float rs0 = srs[0], rs1 = srs[1], rs2 = srs[2], rs3 = srs[3];
  float* outp = out + (((t << 5) + b) << 15);
  #pragma unroll
  for (int ni = 0; ni < 2; ++ni) {
    const int l = L0 + (wl << 5) + (ni << 4) + l15;
    const int ll = l - L0;
    u16 hp[4];
    #pragma unroll
    for (int r = 0; r < 4; ++r) {
      const int c = chq + r;
      float vi = (acc[0][ni][r] - mu0) * rs0 * w4[0][r] + b4[0][r];
      float vf = (acc[1][ni][r] - mu1) * rs1 * w4[1][r] + b4[1][r];
      float vg = (acc[2][ni][r] - mu2) * rs2 * w4[2][r] + b4[2][r];
      float vo = (acc[3][ni][r] - mu3) * rs3 * w4[3][r] + b4[3][r];
      float cyv = sigm(vf) * cxv[ni][r] + sigm(vi) * tanh_f(vg);
      float hyv = sigm(vo) * tanh_f(cyv);
      const int ci = (c << 8) + l;
      cx[(b << 15) + ci] = cyv;
      outp[ci] = hyv;
      hp[r] = f2bf(hyv);
      if (t == 31) {
        out[33554432 + (b << 15) + ci] = hyv;   // final hy
        out[34603008 + (b << 15) + ci] = cyv;   // final cy
      }
    }
    // 8B slot store, slot-swizzled by (ll&3) so granule reads are spread
    *(u64*)(hl + (ll << 6) + (((wm << 5) + (q << 3)) ^ ((ll & 3) << 4))) =
        *(const u64*)hp;
  }
  __syncthreads();

  // ---- cooperative transposed h write: strip cs, this 128 L -> hTw ----
  {
    const int ll = tid >> 2, k = tid & 3;
    const int row = L0 + ll + 2;
    i32x4 v = *(const i32x4*)(hl + (ll << 6) + ((k << 4) ^ ((ll & 3) << 4)));
    char* dst = (char*)hTw + b * 67584 + (row << 8) +
                ((((cs << 2) + k) << 4) ^ ((row & 7) << 4));
    *(i32x4*)dst = v;
  }
}

// ---------- launch ----------
extern "C" void kernel_launch(void* const* d_in, const int* in_sizes, int n_in,
                              void* d_out, int out_size, void* d_ws, size_t ws_size,
                              hipStream_t stream) {
  const float* x  = (const float*)d_in[0];
  const float* cw = (const float*)d_in[1];
  const float* cb = (const float*)d_in[2];
  const float* gw = (const float*)d_in[3];
  const float* gb = (const float*)d_in[4];
  float* out = (float*)d_out;
  char* ws = (char*)d_ws;

  u16*   Wpk   = (u16*)(ws);                 //     983,040 B
  u16*   xT    = (u16*)(ws + 983040);        //  34,603,008 B
  u16*   hT    = (u16*)(ws + 35586048);      //   4,325,376 B (ping-pong)
  float* cx    = (float*)(ws + 39911424);    //   4,194,304 B
  float* stats = (float*)(ws + 44105728);    //     262,144 B
  int*   flags = (int*)(ws + 44367872);      //      32,768 B  (~44.4 MB)

  k_setup<<<3456, 256, 0, stream>>>(cw, Wpk, x, xT, (i32x4*)hT, (i32x4*)cx, (i32x4*)flags);
  for (int t = 0; t < 32; ++t)
    k_step<<<256, 512, 0, stream>>>(Wpk, xT, hT, cb, gw, gb, cx, out, stats, flags, t);
}